// Round 7
// baseline (166.431 us; speedup 1.0000x reference)
//
#include <hip/hip_runtime.h>
#include <stdint.h>

#define HH 8192           // B*H = 16*512 strip height
#define WW 512            // width
#define WPR 8             // uint64 words per row (512/64)
#define TG22F 0.4142135623730951f
#define NPOST 5           // post-fused sweeps (6 closures total)

// ---- workspace layout (bytes) ----
// packed u16 mag|dir<<12 : 8 MiB   @ 0
// buf (strong, in-place) : 512 KiB @ 8388608
// weak bitmap            : 512 KiB @ 8912896
// flags (16 ints)        : 64 B    @ 9437184

__device__ __forceinline__ float to_img(float v) {
    float t = floorf((v + 1.0f) * 0.5f * 255.0f);
    return fminf(fmaxf(t, 0.0f), 255.0f);
}

__device__ __forceinline__ int bsel(uint64_t w0, uint64_t w1, int idx) {
    return (idx < 8) ? (int)((w0 >> (idx * 8)) & 255)
                     : (int)((w1 >> ((idx - 8) * 8)) & 255);
}

// Fill all bits of runs of `w` that contain at least one bit of `s`.
__device__ __forceinline__ uint64_t runfill(uint64_t s, uint64_t w) {
    uint64_t sw = s & w;
    uint64_t up = ((sw + w) ^ w) & w;
    uint64_t rs = __brevll(sw);
    uint64_t rw = __brevll(w);
    uint64_t dn = __brevll(((rs + rw) ^ rw) & rw);
    return up | dn | sw;
}

// Kernel 1: quantize + Sobel (replicate pad on strip) + channel argmax + dir.
// Tile: 32 rows x 64 cols per block, 256 threads, 8 px/thread.
// (Round-5 passing version, verbatim; + flags zeroing in block 0.)
__global__ void k_sobel(const float* __restrict__ in, uint16_t* __restrict__ packed,
                        int* __restrict__ flags) {
    __shared__ uint8_t simg[3 * 34 * 72];
    const int tid = threadIdx.x;
    const int row0 = (blockIdx.x >> 3) << 5;
    const int col0 = (blockIdx.x & 7) << 6;

    if (blockIdx.x == 0 && tid < 16) flags[tid] = 0;   // zero sweep flags

    for (int i = tid; i < 1632; i += 256) {
        int c = i / 544;
        int rem = i - c * 544;
        int hr = rem >> 4;
        int q = rem & 15;
        int gy = row0 + hr - 1;
        gy = gy < 0 ? 0 : (gy >= HH ? HH - 1 : gy);
        int b = gy >> 9, h = gy & 511;
        const float4 v = *(const float4*)&in[((((b * 3 + c) << 9) + h) << 9) + col0 + (q << 2)];
        uint32_t pk = (uint32_t)(uint8_t)to_img(v.x)
                    | ((uint32_t)(uint8_t)to_img(v.y) << 8)
                    | ((uint32_t)(uint8_t)to_img(v.z) << 16)
                    | ((uint32_t)(uint8_t)to_img(v.w) << 24);
        *(uint32_t*)&simg[(c * 34 + hr) * 72 + 4 + (q << 2)] = pk;
    }
    for (int i = tid; i < 204; i += 256) {
        int c = i / 68;
        int rem = i - c * 68;
        int hr = rem >> 1;
        int side = rem & 1;
        int gy = row0 + hr - 1;
        gy = gy < 0 ? 0 : (gy >= HH ? HH - 1 : gy);
        int gc = side ? col0 + 64 : col0 - 1;
        gc = gc < 0 ? 0 : (gc >= WW ? WW - 1 : gc);
        int b = gy >> 9, h = gy & 511;
        float v = to_img(in[((((b * 3 + c) << 9) + h) << 9) + gc]);
        simg[(c * 34 + hr) * 72 + (side ? 68 : 3)] = (uint8_t)v;
    }
    __syncthreads();

    const int r = tid >> 3;
    const int c8 = (tid & 7) << 3;

    int bestMag[8], bgx[8], bgy[8];
    #pragma unroll
    for (int j = 0; j < 8; ++j) { bestMag[j] = -1; bgx[j] = 0; bgy[j] = 0; }

    #pragma unroll
    for (int c = 0; c < 3; ++c) {
        const uint8_t* base = &simg[(c * 34 + r) * 72 + c8];
        uint64_t w00 = *(const uint64_t*)(base);
        uint64_t w01 = *(const uint64_t*)(base + 8);
        uint64_t w10 = *(const uint64_t*)(base + 72);
        uint64_t w11 = *(const uint64_t*)(base + 80);
        uint64_t w20 = *(const uint64_t*)(base + 144);
        uint64_t w21 = *(const uint64_t*)(base + 152);
        int vs[10], t0[10], t2[10];
        #pragma unroll
        for (int i = 0; i < 10; ++i) {
            int a0 = bsel(w00, w01, 3 + i);
            int a1 = bsel(w10, w11, 3 + i);
            int a2 = bsel(w20, w21, 3 + i);
            vs[i] = a0 + 2 * a1 + a2;
            t0[i] = a0; t2[i] = a2;
        }
        #pragma unroll
        for (int j = 0; j < 8; ++j) {
            int gx = vs[j + 2] - vs[j];
            int gy = (t2[j] + 2 * t2[j + 1] + t2[j + 2]) - (t0[j] + 2 * t0[j + 1] + t0[j + 2]);
            int mg = abs(gx) + abs(gy);
            if (mg > bestMag[j]) { bestMag[j] = mg; bgx[j] = gx; bgy[j] = gy; }
        }
    }

    uint32_t res[4];
    #pragma unroll
    for (int jj = 0; jj < 4; ++jj) {
        uint32_t pair = 0;
        #pragma unroll
        for (int s = 0; s < 2; ++s) {
            int j = jj * 2 + s;
            float axf = (float)abs(bgx[j]);
            float ayf = (float)abs(bgy[j]);
            int dir;
            if (ayf < TG22F * axf)      dir = 0;
            else if (ayf * TG22F > axf) dir = 1;
            else                        dir = (bgx[j] * bgy[j] >= 0) ? 2 : 3;
            uint32_t val = (uint32_t)(bestMag[j] | (dir << 12));
            pair |= val << (s * 16);
        }
        res[jj] = pair;
    }
    int y = row0 + r;
    *(uint4*)&packed[y * WW + col0 + c8] = *(uint4*)res;
}

// Kernel 2 (fused NMS + sweep 0): block owns rows [64b, 64b+64).
// Stage packed rows 64b-2..64b+65 into LDS (zeros outside strip), run
// round-5 k_nms per pixel (ballot -> words) for 66 rows (own 64 -> strong+
// weak; halo 2 -> strong only), then the round-5 closure verbatim.
__global__ void __launch_bounds__(256) k_nms_sweep(
        const uint16_t* __restrict__ packed,
        unsigned long long* __restrict__ buf,
        unsigned long long* __restrict__ weakB,
        int* __restrict__ flags)
{
    __shared__ uint16_t spad[68][512];
    __shared__ uint64_t tA[66][8];
    __shared__ uint64_t tB[66][8];
    __shared__ uint64_t wwd[64][8];

    const int tid = threadIdx.x;
    const int b = blockIdx.x;          // 128 blocks x 64 rows
    const int lane = tid & 63;
    const int wave = tid >> 6;

    // ---- stage packed rows 64b-2 .. 64b+65 (68 rows), zeros out of strip ----
    for (int i = tid; i < 4352; i += 256) {       // 68 rows x 64 chunks(8 u16)
        int row = i >> 6;
        int x0 = (i & 63) << 3;
        int y = b * 64 - 2 + row;
        uint4 v = {0u, 0u, 0u, 0u};
        if (y >= 0 && y < HH) v = *(const uint4*)&packed[y * WW + x0];
        *(uint4*)&spad[row][x0] = v;
    }
    __syncthreads();

    // ---- NMS for 66 rows x 8 words; round-5 k_nms math on staged data ----
    for (int t = wave; t < 528; t += 4) {
        int row_m = t >> 3;            // 0..65; tA row index
        int k = t & 7;
        int y = b * 64 - 1 + row_m;    // strip row
        int ry = row_m + 1;            // spad row
        int x = (k << 6) + lane;
        uint16_t own = spad[ry][x];
        int mag = own & 0xFFF;
        int dir = own >> 12;
        int d1y = (dir == 0) ? 0 : -1;
        int d1x = (dir == 0) ? -1 : (dir == 1) ? 0 : (dir == 2) ? -1 : 1;
        int n1y = y + d1y, n1x = x + d1x;
        int n2y = y - d1y, n2x = x - d1x;
        int n1 = (n1y >= 0 && n1y < HH && n1x >= 0 && n1x < WW)
                 ? (spad[ry + d1y][n1x] & 0xFFF) : 0;
        int n2 = (n2y >= 0 && n2y < HH && n2x >= 0 && n2x < WW)
                 ? (spad[ry - d1y][n2x] & 0xFFF) : 0;
        bool keep = (mag > n1) && (mag >= n2);
        bool strong = keep && (mag > 200);
        bool weak   = keep && (mag > 100);
        unsigned long long sb = __ballot(strong ? 1 : 0);
        unsigned long long wb = __ballot(weak ? 1 : 0);
        if (lane == 0) {
            tA[row_m][k] = sb;
            if (row_m >= 1 && row_m <= 64) wwd[row_m - 1][k] = wb;
        }
    }
    __syncthreads();

    // ---- closure (round-5 k_sweep verbatim, tA/wwd-fed) ----
    const int r = tid >> 3;
    const int k = tid & 7;
    const int g0 = (b * 64 + r) * WPR + k;
    const int g1 = g0 + 32 * WPR;
    const uint64_t wk0 = wwd[r][k];
    const uint64_t wk1 = wwd[r + 32][k];
    const uint64_t l0 = tA[r + 1][k];
    const uint64_t l1 = tA[r + 33][k];
    if (tid < 8)       tB[0][tid] = tA[0][tid];
    else if (tid < 16) tB[65][tid - 8] = tA[65][tid - 8];

    uint64_t (*src)[8] = tA;
    uint64_t (*dst)[8] = tB;
    uint64_t o0 = l0, o1 = l1;
    for (;;) {
        uint64_t acc0 = 0, acc1 = 0;
        #pragma unroll
        for (int dr = 0; dr < 3; ++dr) {
            uint64_t c0v = src[r + dr][k];
            uint64_t h0 = c0v | (c0v << 1) | (c0v >> 1);
            if (k > 0) h0 |= src[r + dr][k - 1] >> 63;
            if (k < 7) h0 |= src[r + dr][k + 1] << 63;
            acc0 |= h0;
            uint64_t c1v = src[r + 32 + dr][k];
            uint64_t h1 = c1v | (c1v << 1) | (c1v >> 1);
            if (k > 0) h1 |= src[r + 32 + dr][k - 1] >> 63;
            if (k < 7) h1 |= src[r + 32 + dr][k + 1] << 63;
            acc1 |= h1;
        }
        uint64_t n0 = runfill(o0 | (acc0 & wk0), wk0);
        uint64_t n1 = runfill(o1 | (acc1 & wk1), wk1);
        dst[r + 1][k]  = n0;
        dst[r + 33][k] = n1;
        int any = __syncthreads_or((int)((n0 != o0) | (n1 != o1)));
        o0 = n0; o1 = n1;
        uint64_t (*t)[8] = src; src = dst; dst = t;
        if (!any) break;
    }
    buf[g0] = o0;                 // always write: buf starts poisoned
    buf[g1] = o1;
    weakB[g0] = wk0;
    weakB[g1] = wk1;
    bool ch = (o0 != l0) || (o1 != l1);
    if (__ballot(ch ? 1 : 0) != 0ull && (tid & 63) == 0)
        __hip_atomic_store(&flags[0], 1, __ATOMIC_RELAXED, __HIP_MEMORY_SCOPE_AGENT);
}

// Kernel 3: one hysteresis sweep (round-5 passing version, verbatim).
__global__ void __launch_bounds__(256) k_sweep(
        const unsigned long long* __restrict__ weakB,
        unsigned long long* __restrict__ buf,
        int* __restrict__ flags, int sidx)
{
    if (flags[sidx - 1] == 0) return;
    __shared__ uint64_t tA[66][8];
    __shared__ uint64_t tB[66][8];
    const int tid = threadIdx.x;
    const int b = blockIdx.x;          // 128 blocks x 64 rows
    const int r = tid >> 3;
    const int k = tid & 7;
    const int g0 = (b * 64 + r) * WPR + k;
    const int g1 = g0 + 32 * WPR;
    const uint64_t wk0 = weakB[g0];
    const uint64_t wk1 = weakB[g1];
    const uint64_t l0 = buf[g0];
    const uint64_t l1 = buf[g1];
    tA[r + 1][k]  = l0;
    tA[r + 33][k] = l1;
    if (tid < 8) {
        uint64_t h = (b > 0) ? buf[(b * 64 - 1) * WPR + tid] : 0ull;
        tA[0][tid] = h; tB[0][tid] = h;
    } else if (tid < 16) {
        int kk = tid - 8;
        uint64_t h = (b < 127) ? buf[(b * 64 + 64) * WPR + kk] : 0ull;
        tA[65][kk] = h; tB[65][kk] = h;
    }
    __syncthreads();

    uint64_t (*src)[8] = tA;
    uint64_t (*dst)[8] = tB;
    uint64_t o0 = l0, o1 = l1;
    for (;;) {
        uint64_t acc0 = 0, acc1 = 0;
        #pragma unroll
        for (int dr = 0; dr < 3; ++dr) {
            uint64_t c0v = src[r + dr][k];
            uint64_t h0 = c0v | (c0v << 1) | (c0v >> 1);
            if (k > 0) h0 |= src[r + dr][k - 1] >> 63;
            if (k < 7) h0 |= src[r + dr][k + 1] << 63;
            acc0 |= h0;
            uint64_t c1v = src[r + 32 + dr][k];
            uint64_t h1 = c1v | (c1v << 1) | (c1v >> 1);
            if (k > 0) h1 |= src[r + 32 + dr][k - 1] >> 63;
            if (k < 7) h1 |= src[r + 32 + dr][k + 1] << 63;
            acc1 |= h1;
        }
        uint64_t n0 = runfill(o0 | (acc0 & wk0), wk0);
        uint64_t n1 = runfill(o1 | (acc1 & wk1), wk1);
        dst[r + 1][k]  = n0;
        dst[r + 33][k] = n1;
        int any = __syncthreads_or((int)((n0 != o0) | (n1 != o1)));
        o0 = n0; o1 = n1;
        uint64_t (*t)[8] = src; src = dst; dst = t;
        if (!any) break;
    }
    bool ch = (o0 != l0) || (o1 != l1);
    if (o0 != l0) buf[g0] = o0;
    if (o1 != l1) buf[g1] = o1;
    if (__ballot(ch ? 1 : 0) != 0ull && (tid & 63) == 0)
        __hip_atomic_store(&flags[sidx], 1, __ATOMIC_RELAXED, __HIP_MEMORY_SCOPE_AGENT);
}

// Kernel 4: expand bitmap -> (16,3,512,512) f32 output in {-1,+1}, float4.
__global__ void k_out(const unsigned long long* __restrict__ result, float* __restrict__ out) {
    int t = blockIdx.x * blockDim.x + threadIdx.x;
    int b = t >> 16;
    int r = t & 65535;
    int h = r >> 7;
    int w = (r & 127) << 2;
    int y = (b << 9) + h;
    unsigned long long word = result[y * WPR + (w >> 6)];
    int sh = w & 63;
    float4 v;
    v.x = ((word >> (sh + 0)) & 1ull) ? 1.0f : -1.0f;
    v.y = ((word >> (sh + 1)) & 1ull) ? 1.0f : -1.0f;
    v.z = ((word >> (sh + 2)) & 1ull) ? 1.0f : -1.0f;
    v.w = ((word >> (sh + 3)) & 1ull) ? 1.0f : -1.0f;
    int base = (b * 3) << 18;
    int off = (h << 9) + w;
    *(float4*)&out[base + off] = v;
    *(float4*)&out[base + 262144 + off] = v;
    *(float4*)&out[base + 524288 + off] = v;
}

extern "C" void kernel_launch(void* const* d_in, const int* in_sizes, int n_in,
                              void* d_out, int out_size, void* d_ws, size_t ws_size,
                              hipStream_t stream) {
    const float* x = (const float*)d_in[0];
    float* out = (float*)d_out;
    char* ws = (char*)d_ws;

    uint16_t* packed          = (uint16_t*)(ws);
    unsigned long long* buf   = (unsigned long long*)(ws + 8388608);
    unsigned long long* weakB = (unsigned long long*)(ws + 8912896);
    int* flags                = (int*)(ws + 9437184);

    k_sobel<<<2048, 256, 0, stream>>>(x, packed, flags);
    k_nms_sweep<<<128, 256, 0, stream>>>(packed, buf, weakB, flags);
    for (int s = 1; s <= NPOST; ++s)
        k_sweep<<<128, 256, 0, stream>>>(weakB, buf, flags, s);
    k_out<<<4096, 256, 0, stream>>>(buf, out);
}

// Round 8
// 137.966 us; speedup vs baseline: 1.2063x; 1.2063x over previous
//
#include <hip/hip_runtime.h>
#include <stdint.h>

#define HH 8192           // B*H = 16*512 strip height
#define WW 512            // width
#define WPR 8             // uint64 words per row (512/64)
#define TG22F 0.4142135623730951f
#define NSWEEP 6

// ---- workspace layout (bytes) ----
// packed u16 mag|dir<<12 : 8 MiB   @ 0
// buf (strong, in-place) : 512 KiB @ 8388608
// weak bitmap            : 512 KiB @ 8912896
// flags (16 ints)        : 64 B    @ 9437184

__device__ __forceinline__ float to_img(float v) {
    float t = floorf((v + 1.0f) * 0.5f * 255.0f);
    return fminf(fmaxf(t, 0.0f), 255.0f);
}

__device__ __forceinline__ int bsel(uint64_t w0, uint64_t w1, int idx) {
    return (idx < 8) ? (int)((w0 >> (idx * 8)) & 255)
                     : (int)((w1 >> ((idx - 8) * 8)) & 255);
}

// Fill all bits of runs of `w` that contain at least one bit of `s`.
__device__ __forceinline__ uint64_t runfill(uint64_t s, uint64_t w) {
    uint64_t sw = s & w;
    uint64_t up = ((sw + w) ^ w) & w;
    uint64_t rs = __brevll(sw);
    uint64_t rw = __brevll(w);
    uint64_t dn = __brevll(((rs + rw) ^ rw) & rw);
    return up | dn | sw;
}

// 64-bit shuffles via two 32-bit halves (avoid 64-bit shfl overloads).
__device__ __forceinline__ uint64_t shfl_up64(uint64_t v, int d) {
    int lo = __shfl_up((int)(uint32_t)v, d, 64);
    int hi = __shfl_up((int)(uint32_t)(v >> 32), d, 64);
    return ((uint64_t)(uint32_t)hi << 32) | (uint32_t)lo;
}
__device__ __forceinline__ uint64_t shfl_dn64(uint64_t v, int d) {
    int lo = __shfl_down((int)(uint32_t)v, d, 64);
    int hi = __shfl_down((int)(uint32_t)(v >> 32), d, 64);
    return ((uint64_t)(uint32_t)hi << 32) | (uint32_t)lo;
}

// Kernel 1: quantize + Sobel (replicate pad on strip) + channel argmax + dir.
// (Round-5 passing version, verbatim.)
__global__ void k_sobel(const float* __restrict__ in, uint16_t* __restrict__ packed) {
    __shared__ uint8_t simg[3 * 34 * 72];
    const int tid = threadIdx.x;
    const int row0 = (blockIdx.x >> 3) << 5;
    const int col0 = (blockIdx.x & 7) << 6;

    for (int i = tid; i < 1632; i += 256) {
        int c = i / 544;
        int rem = i - c * 544;
        int hr = rem >> 4;
        int q = rem & 15;
        int gy = row0 + hr - 1;
        gy = gy < 0 ? 0 : (gy >= HH ? HH - 1 : gy);
        int b = gy >> 9, h = gy & 511;
        const float4 v = *(const float4*)&in[((((b * 3 + c) << 9) + h) << 9) + col0 + (q << 2)];
        uint32_t pk = (uint32_t)(uint8_t)to_img(v.x)
                    | ((uint32_t)(uint8_t)to_img(v.y) << 8)
                    | ((uint32_t)(uint8_t)to_img(v.z) << 16)
                    | ((uint32_t)(uint8_t)to_img(v.w) << 24);
        *(uint32_t*)&simg[(c * 34 + hr) * 72 + 4 + (q << 2)] = pk;
    }
    for (int i = tid; i < 204; i += 256) {
        int c = i / 68;
        int rem = i - c * 68;
        int hr = rem >> 1;
        int side = rem & 1;
        int gy = row0 + hr - 1;
        gy = gy < 0 ? 0 : (gy >= HH ? HH - 1 : gy);
        int gc = side ? col0 + 64 : col0 - 1;
        gc = gc < 0 ? 0 : (gc >= WW ? WW - 1 : gc);
        int b = gy >> 9, h = gy & 511;
        float v = to_img(in[((((b * 3 + c) << 9) + h) << 9) + gc]);
        simg[(c * 34 + hr) * 72 + (side ? 68 : 3)] = (uint8_t)v;
    }
    __syncthreads();

    const int r = tid >> 3;
    const int c8 = (tid & 7) << 3;

    int bestMag[8], bgx[8], bgy[8];
    #pragma unroll
    for (int j = 0; j < 8; ++j) { bestMag[j] = -1; bgx[j] = 0; bgy[j] = 0; }

    #pragma unroll
    for (int c = 0; c < 3; ++c) {
        const uint8_t* base = &simg[(c * 34 + r) * 72 + c8];
        uint64_t w00 = *(const uint64_t*)(base);
        uint64_t w01 = *(const uint64_t*)(base + 8);
        uint64_t w10 = *(const uint64_t*)(base + 72);
        uint64_t w11 = *(const uint64_t*)(base + 80);
        uint64_t w20 = *(const uint64_t*)(base + 144);
        uint64_t w21 = *(const uint64_t*)(base + 152);
        int vs[10], t0[10], t2[10];
        #pragma unroll
        for (int i = 0; i < 10; ++i) {
            int a0 = bsel(w00, w01, 3 + i);
            int a1 = bsel(w10, w11, 3 + i);
            int a2 = bsel(w20, w21, 3 + i);
            vs[i] = a0 + 2 * a1 + a2;
            t0[i] = a0; t2[i] = a2;
        }
        #pragma unroll
        for (int j = 0; j < 8; ++j) {
            int gx = vs[j + 2] - vs[j];
            int gy = (t2[j] + 2 * t2[j + 1] + t2[j + 2]) - (t0[j] + 2 * t0[j + 1] + t0[j + 2]);
            int mg = abs(gx) + abs(gy);
            if (mg > bestMag[j]) { bestMag[j] = mg; bgx[j] = gx; bgy[j] = gy; }
        }
    }

    uint32_t res[4];
    #pragma unroll
    for (int jj = 0; jj < 4; ++jj) {
        uint32_t pair = 0;
        #pragma unroll
        for (int s = 0; s < 2; ++s) {
            int j = jj * 2 + s;
            float axf = (float)abs(bgx[j]);
            float ayf = (float)abs(bgy[j]);
            int dir;
            if (ayf < TG22F * axf)      dir = 0;
            else if (ayf * TG22F > axf) dir = 1;
            else                        dir = (bgx[j] * bgy[j] >= 0) ? 2 : 3;
            uint32_t val = (uint32_t)(bestMag[j] | (dir << 12));
            pair |= val << (s * 16);
        }
        res[jj] = pair;
    }
    int y = row0 + r;
    *(uint4*)&packed[y * WW + col0 + c8] = *(uint4*)res;
}

// Kernel 2: NMS (zero pad on strip) -> strong/weak bitmaps via wave ballot.
// Also zeroes the sweep flags (block 0 only). (Round-5 passing, verbatim.)
__global__ void k_nms(const uint16_t* __restrict__ packed,
                      unsigned long long* __restrict__ strongB,
                      unsigned long long* __restrict__ weakB,
                      int* __restrict__ flags) {
    if (blockIdx.x == 0 && threadIdx.x < 16) flags[threadIdx.x] = 0;
    int y = blockIdx.x >> 1;
    int x = ((blockIdx.x & 1) << 8) + threadIdx.x;
    uint16_t own = packed[y * WW + x];
    int mag = own & 0xFFF;
    int dir = own >> 12;
    int d1y = (dir == 0) ? 0 : -1;
    int d1x = (dir == 0) ? -1 : (dir == 1) ? 0 : (dir == 2) ? -1 : 1;
    int n1y = y + d1y, n1x = x + d1x;
    int n2y = y - d1y, n2x = x - d1x;
    int n1 = (n1y >= 0 && n1y < HH && n1x >= 0 && n1x < WW) ? (packed[n1y * WW + n1x] & 0xFFF) : 0;
    int n2 = (n2y >= 0 && n2y < HH && n2x >= 0 && n2x < WW) ? (packed[n2y * WW + n2x] & 0xFFF) : 0;
    bool keep = (mag > n1) && (mag >= n2);
    bool strong = keep && (mag > 200);
    bool weak   = keep && (mag > 100);
    unsigned long long sb = __ballot(strong ? 1 : 0);
    unsigned long long wb = __ballot(weak ? 1 : 0);
    if ((threadIdx.x & 63) == 0) {
        int word = y * WPR + (x >> 6);
        strongB[word] = sb;
        weakB[word]   = wb;
    }
}

// Kernel 3: wave-local hysteresis sweep. Each wave owns a 64-row x 512-col
// band entirely in registers (lane = row, 8 uint64/lane). Vertical neighbor
// spreads via 32-bit shuffles; horizontal runfill + cross-word carries fully
// dynamic in-lane. No LDS, no barriers; convergence via __ballot. Band halo
// rows static per sweep (same operator & boundaries as round-5 k_sweep ->
// same fixed point). Early-exit via cross-launch flags.
__global__ void __launch_bounds__(256) k_wsweep(
        const unsigned long long* __restrict__ weakB,
        unsigned long long* __restrict__ buf,
        int* __restrict__ flags, int sidx)
{
    if (sidx > 0 && flags[sidx - 1] == 0) return;
    const int lane = threadIdx.x & 63;
    const int wave = (blockIdx.x << 2) + (threadIdx.x >> 6);   // 0..127
    const int base = ((wave << 6) + lane) * WPR;               // own row

    uint64_t own[8], wk[8];
    #pragma unroll
    for (int k = 0; k < 8; ++k) { wk[k] = weakB[base + k]; own[k] = buf[base + k]; }

    // static halo rows: lane 0 uses band-above's last row, lane 63 band-below's first
    uint64_t hu[8], hd[8];
    #pragma unroll
    for (int k = 0; k < 8; ++k) { hu[k] = 0; hd[k] = 0; }
    if (lane == 0 && wave > 0) {
        #pragma unroll
        for (int k = 0; k < 8; ++k) hu[k] = buf[base - WPR + k];
    }
    if (lane == 63 && wave < 127) {
        #pragma unroll
        for (int k = 0; k < 8; ++k) hd[k] = buf[base + WPR + k];
    }
    uint64_t hspu[8], hspd[8];
    #pragma unroll
    for (int k = 0; k < 8; ++k) {
        uint64_t a = hu[k] | (hu[k] << 1) | (hu[k] >> 1);
        if (k > 0) a |= hu[k - 1] >> 63;
        if (k < 7) a |= hu[k + 1] << 63;
        hspu[k] = a;
        uint64_t b = hd[k] | (hd[k] << 1) | (hd[k] >> 1);
        if (k > 0) b |= hd[k - 1] >> 63;
        if (k < 7) b |= hd[k + 1] << 63;
        hspd[k] = b;
    }

    bool grew = false;
    for (;;) {
        uint64_t sp[8];
        #pragma unroll
        for (int k = 0; k < 8; ++k) {
            uint64_t h = own[k] | (own[k] << 1) | (own[k] >> 1);
            if (k > 0) h |= own[k - 1] >> 63;
            if (k < 7) h |= own[k + 1] << 63;
            sp[k] = h;
        }
        uint64_t su[8], sd[8];
        #pragma unroll
        for (int k = 0; k < 8; ++k) {
            su[k] = shfl_up64(sp[k], 1);
            sd[k] = shfl_dn64(sp[k], 1);
        }
        if (lane == 0) {
            #pragma unroll
            for (int k = 0; k < 8; ++k) su[k] = hspu[k];
        }
        if (lane == 63) {
            #pragma unroll
            for (int k = 0; k < 8; ++k) sd[k] = hspd[k];
        }
        uint32_t ch = 0;
        #pragma unroll
        for (int k = 0; k < 8; ++k) {
            uint64_t acc = sp[k] | su[k] | sd[k];
            uint64_t nv = runfill(own[k] | (acc & wk[k]), wk[k]);
            ch |= (uint32_t)(nv != own[k]);
            own[k] = nv;
        }
        if (ch) grew = true;
        if (__ballot(ch ? 1 : 0) == 0ull) break;   // wave-uniform
    }

    // monotone: grew  <=>  final != initially-loaded
    if (__ballot(grew ? 1 : 0) != 0ull) {
        #pragma unroll
        for (int k = 0; k < 8; ++k) buf[base + k] = own[k];
        if (lane == 0)
            __hip_atomic_store(&flags[sidx], 1, __ATOMIC_RELAXED, __HIP_MEMORY_SCOPE_AGENT);
    }
}

// Kernel 4: expand bitmap -> (16,3,512,512) f32 output in {-1,+1}, float4.
__global__ void k_out(const unsigned long long* __restrict__ result, float* __restrict__ out) {
    int t = blockIdx.x * blockDim.x + threadIdx.x;
    int b = t >> 16;
    int r = t & 65535;
    int h = r >> 7;
    int w = (r & 127) << 2;
    int y = (b << 9) + h;
    unsigned long long word = result[y * WPR + (w >> 6)];
    int sh = w & 63;
    float4 v;
    v.x = ((word >> (sh + 0)) & 1ull) ? 1.0f : -1.0f;
    v.y = ((word >> (sh + 1)) & 1ull) ? 1.0f : -1.0f;
    v.z = ((word >> (sh + 2)) & 1ull) ? 1.0f : -1.0f;
    v.w = ((word >> (sh + 3)) & 1ull) ? 1.0f : -1.0f;
    int base = (b * 3) << 18;
    int off = (h << 9) + w;
    *(float4*)&out[base + off] = v;
    *(float4*)&out[base + 262144 + off] = v;
    *(float4*)&out[base + 524288 + off] = v;
}

extern "C" void kernel_launch(void* const* d_in, const int* in_sizes, int n_in,
                              void* d_out, int out_size, void* d_ws, size_t ws_size,
                              hipStream_t stream) {
    const float* x = (const float*)d_in[0];
    float* out = (float*)d_out;
    char* ws = (char*)d_ws;

    uint16_t* packed          = (uint16_t*)(ws);
    unsigned long long* buf   = (unsigned long long*)(ws + 8388608);
    unsigned long long* weakB = (unsigned long long*)(ws + 8912896);
    int* flags                = (int*)(ws + 9437184);

    k_sobel<<<2048, 256, 0, stream>>>(x, packed);
    k_nms<<<HH * 2, 256, 0, stream>>>(packed, buf, weakB, flags);
    for (int s = 0; s < NSWEEP; ++s)
        k_wsweep<<<32, 256, 0, stream>>>(weakB, buf, flags, s);
    k_out<<<4096, 256, 0, stream>>>(buf, out);
}